// Round 13
// baseline (58.034 us; speedup 1.0000x reference)
//
#include <hip/hip_runtime.h>
#include <stdint.h>

// KeepTopN: inputs (32, 56, 56, 256) f32, n = 48 (k-th largest per row).
// v13 = v12 with ONE change: the streaming pass stores d*0.0f instead of a
// constant zero. This gives every store a data dependency on its load --
// the exact pacing structure of the 6.3 TB/s copy microbenchmark -- instead
// of letting independent zero-stores flood the VMEM queue ahead of the
// loads. Output is bitwise identical (ref computes x*0 for masked lanes too).
//   k_scan  : copy-paced stream, bitmap of candidates (bit per 2 float4s).
//   k_gather: 1568 blocks decode bitmap, re-fetch flagged f4 pairs
//             (cache-hit), append u16 positions to per-tile slots.
//   k_sel   : parallel exact radix-select + scatter survivors; inline
//             full-row fallback (never taken on N(0,1) data).
#define ROWS 32
#define ROW_LEN 802816         // 56*56*256
#define ROW_LEN4 200704        // ROW_LEN / 4
#define THREADS 256

#define SBPR 49                // tiles per row
#define TILE_F4 4096           // float4 per tile
#define TILE_EL 16384          // elements per tile (u16-indexable)
#define F4_PT 16               // float4 per thread per tile
#define SCAN_BLOCKS (ROWS * SBPR)   // 1568
#define TG 3.0f                // speculative threshold; E[cand/tile] ~= 22
#define BCAP 96                // per-tile candidate cap (huge margin)
#define CAP_ROW (SBPR * BCAP)  // 4704
#define SLOTS_PT 19            // ceil(4704/256)

// ws layout (bytes), ~709 KB total footprint (proven in v12):
//   bm    : u8[SCAN_BLOCKS][THREADS]  @ 0       (401408)  always rewritten
//   pos16 : u16[SCAN_BLOCKS][BCAP]    @ 401408  (301056)  slots
//   bcnt  : i32[SCAN_BLOCKS]          @ 702464  (6272)    always rewritten
//   thr   : f32[ROWS]                 @ 708736  (128)
#define OFF_POS  401408
#define OFF_BCNT 702464
#define OFF_THR  708736

// Monotone order-preserving f32 -> u32 key (larger float -> larger key).
__device__ __forceinline__ uint32_t fkey(float x) {
    uint32_t u = __float_as_uint(x);
    return (u & 0x80000000u) ? ~u : (u | 0x80000000u);
}
__device__ __forceinline__ float fkey_inv(uint32_t k) {
    uint32_t u = (k & 0x80000000u) ? (k & 0x7FFFFFFFu) : ~k;
    return __uint_as_float(u);
}

// Pass 1: copy-paced stream. Read input, write x*0 to out (store depends on
// load -> 1:1 load/store interleave like the copy ubench), accumulate an
// 8-bit candidate mask in a register, one u8 store per thread at the end.
// Bit b of (tile,t) covers f4 indices {2b*THREADS+t, (2b+1)*THREADS+t}.
__global__ __launch_bounds__(THREADS) void k_scan(const float* __restrict__ in,
                                                  float* __restrict__ out,
                                                  uint8_t* __restrict__ bm) {
    const int bid = blockIdx.x;
    const size_t base = (size_t)bid * TILE_F4 + threadIdx.x;
    const float4* p = (const float4*)in + base;
    float4* q = (float4*)out + base;
    uint32_t cm = 0;
#pragma unroll
    for (int it = 0; it < F4_PT; ++it) {
        const float4 d = p[it * THREADS];
        float4 z;
        z.x = d.x * 0.0f; z.y = d.y * 0.0f; z.z = d.z * 0.0f; z.w = d.w * 0.0f;
        q[it * THREADS] = z;
        const float mx = fmaxf(fmaxf(d.x, d.y), fmaxf(d.z, d.w));
        cm |= (mx > TG) ? (1u << (it >> 1)) : 0u;
    }
    bm[(size_t)bid * THREADS + threadIdx.x] = (uint8_t)cm;
}

// Pass 2: per tile, decode bitmap and append candidate positions to slots.
__global__ __launch_bounds__(THREADS) void k_gather(const float* __restrict__ in,
                                                    const uint8_t* __restrict__ bm,
                                                    uint16_t* __restrict__ pos16,
                                                    int* __restrict__ bcnt) {
    __shared__ uint32_t lp[BCAP];
    __shared__ int lcnt;
    const int bid = blockIdx.x;
    if (threadIdx.x == 0) lcnt = 0;
    __syncthreads();
    const float4* p = (const float4*)in + (size_t)bid * TILE_F4;
    uint32_t cm = bm[(size_t)bid * THREADS + threadIdx.x];
    while (cm) {
        const int b = __builtin_ctz(cm);
        cm &= cm - 1;
#pragma unroll
        for (int half = 0; half < 2; ++half) {
            const uint32_t fi = (uint32_t)(2 * b + half) * THREADS + threadIdx.x;
            const float4 d = p[fi];
            const uint32_t e = fi * 4u;
            if (d.x > TG) { int j = atomicAdd(&lcnt, 1); if (j < BCAP) lp[j] = e + 0u; }
            if (d.y > TG) { int j = atomicAdd(&lcnt, 1); if (j < BCAP) lp[j] = e + 1u; }
            if (d.z > TG) { int j = atomicAdd(&lcnt, 1); if (j < BCAP) lp[j] = e + 2u; }
            if (d.w > TG) { int j = atomicAdd(&lcnt, 1); if (j < BCAP) lp[j] = e + 3u; }
        }
    }
    __syncthreads();
    const int c = lcnt;
    if (threadIdx.x == 0) bcnt[bid] = c;   // raw; overflow detected in k_sel
    const int cc = c < BCAP ? c : BCAP;
    for (int i = threadIdx.x; i < cc; i += THREADS)
        pos16[(size_t)bid * BCAP + i] = (uint16_t)lp[i];
}

// Parallel digit pick: histogram h[256] -> inclusive suffix scan across the
// 256 threads (Hillis-Steele, 8 steps) -> digit d with S[d] >= r > S[d+1].
__device__ __forceinline__ void pick_digit(uint32_t* h, int t, int r,
                                           int* sh_sel, int* sh_rank) {
#pragma unroll
    for (int off = 1; off < 256; off <<= 1) {
        uint32_t v = h[t] + ((t + off < 256) ? h[t + off] : 0u);
        __syncthreads();
        h[t] = v;
        __syncthreads();
    }
    const uint32_t Sd = h[t];
    const uint32_t Sd1 = (t < 255) ? h[t + 1] : 0u;
    if ((int)Sd >= r && (int)Sd1 < r) { *sh_sel = t; *sh_rank = r - (int)Sd1; }
    __syncthreads();
}

// Pass 3: per row: gather candidate keys (cache-resident input), exact
// 4x8-bit radix select of the n-th largest, scatter survivors into the
// zeroed output. Fallback (!ok): full-row radix + full-row masked write.
__global__ __launch_bounds__(THREADS) void k_sel(const float* __restrict__ in,
                                                 const int* __restrict__ n_ptr,
                                                 const int* __restrict__ bcnt,
                                                 const uint16_t* __restrict__ pos16,
                                                 float* __restrict__ out,
                                                 float* __restrict__ thr) {
    __shared__ int lb[SBPR];
    __shared__ uint32_t h[256];
    __shared__ int sh_sel, sh_rank, sh_m, sh_bad;
    const int row = blockIdx.x;
    const int t = threadIdx.x;
    const int n = *n_ptr;
    const float* rin = in + (size_t)row * ROW_LEN;
    float* rout = out + (size_t)row * ROW_LEN;

    if (t == 0) { sh_m = 0; sh_bad = 0; }
    __syncthreads();
    {
        int lsum = 0, lbad = 0;
        for (int b = t; b < SBPR; b += THREADS) {
            const int c = bcnt[row * SBPR + b];
            lbad |= (c > BCAP);
            const int cc = c < BCAP ? c : BCAP;
            lb[b] = cc;
            lsum += cc;
        }
        if (lsum) atomicAdd(&sh_m, lsum);
        if (lbad) atomicOr(&sh_bad, 1);
    }
    __syncthreads();
    const int m = sh_m;
    const bool ok = (!sh_bad) && (m >= n) && (n >= 1);

    if (ok) {
        // Coalesced slot load + gathered key fetch (cache-resident input).
        uint32_t key[SLOTS_PT];
        uint32_t ps[SLOTS_PT];
        bool val[SLOTS_PT];
#pragma unroll
        for (int j = 0; j < SLOTS_PT; ++j) {
            const int slot = j * THREADS + t;
            uint32_t k = 0, pp = 0; bool v = false;
            if (slot < CAP_ROW) {
                const int b = slot / BCAP;
                v = (slot - b * BCAP) < lb[b];
                if (v) {
                    pp = (uint32_t)b * TILE_EL + pos16[(size_t)(row * SBPR) * BCAP + slot];
                    k = fkey(rin[pp]);
                }
            }
            key[j] = k; ps[j] = pp; val[j] = v;
        }
        uint32_t prefix = 0, msk = 0;
        int r = n;
        for (int rd = 0; rd < 4; ++rd) {
            const int shn = 24 - rd * 8;
            h[t] = 0;
            __syncthreads();
#pragma unroll
            for (int j = 0; j < SLOTS_PT; ++j)
                if (val[j] && (key[j] & msk) == prefix)
                    atomicAdd(&h[(key[j] >> shn) & 255u], 1u);
            __syncthreads();
            pick_digit(h, t, r, &sh_sel, &sh_rank);
            prefix |= ((uint32_t)sh_sel) << shn;
            msk |= 255u << shn;
            r = sh_rank;
            __syncthreads();
        }
        // Scatter survivors (key >= prefix <=> value >= threshold).
#pragma unroll
        for (int j = 0; j < SLOTS_PT; ++j)
            if (val[j] && key[j] >= prefix)
                rout[ps[j]] = fkey_inv(key[j]);
        if (t == 0) thr[row] = fkey_inv(prefix);
    } else {
        // Exact fallback: full-row radix select + full-row masked write.
        uint32_t prefix = 0, msk = 0;
        int r = (n < 1) ? 1 : n;
        const float4* p = (const float4*)rin;
        for (int rd = 0; rd < 4; ++rd) {
            const int shn = 24 - rd * 8;
            h[t] = 0;
            __syncthreads();
            for (int i = t; i < ROW_LEN4; i += THREADS) {
                const float4 d = p[i];
                uint32_t k;
                k = fkey(d.x); if ((k & msk) == prefix) atomicAdd(&h[(k >> shn) & 255u], 1u);
                k = fkey(d.y); if ((k & msk) == prefix) atomicAdd(&h[(k >> shn) & 255u], 1u);
                k = fkey(d.z); if ((k & msk) == prefix) atomicAdd(&h[(k >> shn) & 255u], 1u);
                k = fkey(d.w); if ((k & msk) == prefix) atomicAdd(&h[(k >> shn) & 255u], 1u);
            }
            __syncthreads();
            pick_digit(h, t, r, &sh_sel, &sh_rank);
            prefix |= ((uint32_t)sh_sel) << shn;
            msk |= 255u << shn;
            r = sh_rank;
            __syncthreads();
        }
        const float tf = fkey_inv(prefix);
        float4* q = (float4*)rout;
        for (int i = t; i < ROW_LEN4; i += THREADS) {
            float4 d = p[i];
            d.x = (d.x >= tf) ? d.x : 0.0f;
            d.y = (d.y >= tf) ? d.y : 0.0f;
            d.z = (d.z >= tf) ? d.z : 0.0f;
            d.w = (d.w >= tf) ? d.w : 0.0f;
            q[i] = d;
        }
        if (t == 0) thr[row] = tf;
    }
}

extern "C" void kernel_launch(void* const* d_in, const int* in_sizes, int n_in,
                              void* d_out, int out_size, void* d_ws, size_t ws_size,
                              hipStream_t stream) {
    const float* in = (const float*)d_in[0];
    const int* n_ptr = (const int*)d_in[1];
    float* out = (float*)d_out;
    char* ws = (char*)d_ws;

    uint8_t* bm = (uint8_t*)ws;
    uint16_t* pos16 = (uint16_t*)(ws + OFF_POS);
    int* bcnt = (int*)(ws + OFF_BCNT);
    float* thr = (float*)(ws + OFF_THR);

    k_scan<<<SCAN_BLOCKS, THREADS, 0, stream>>>(in, out, bm);
    k_gather<<<SCAN_BLOCKS, THREADS, 0, stream>>>(in, bm, pos16, bcnt);
    k_sel<<<ROWS, THREADS, 0, stream>>>(in, n_ptr, bcnt, pos16, out, thr);
}

// Round 14
// 52.992 us; speedup vs baseline: 1.0951x; 1.0951x over previous
//
#include <hip/hip_runtime.h>
#include <stdint.h>

// KeepTopN: inputs (32, 56, 56, 256) f32, n = 48 (k-th largest per row).
// v14: WAVE-SPECIALIZED streaming pass: 512-thread blocks; waves 0-3 run a
// pure-READ scan (load+fmax+register bitmap), waves 4-7 run a pure-WRITE
// zero-fill of the same tile. Both streams are co-resident on the CU
// (separate waves co-schedule, m114), no intra-wave read/write mixing --
// each stream keeps its proven pure-stream form. k_gather/k_sel unchanged
// from v12 (cheap, proven). Inline full-row fallback keeps correctness
// unconditional.
#define ROWS 32
#define ROW_LEN 802816         // 56*56*256
#define ROW_LEN4 200704        // ROW_LEN / 4
#define THREADS 256            // k_gather / k_sel block size
#define SCAN_THREADS 512       // k_scan: 4 read waves + 4 write waves

#define SBPR 49                // tiles per row
#define TILE_F4 4096           // float4 per tile
#define TILE_EL 16384          // elements per tile (u16-indexable)
#define F4_PT 16               // float4 per 256-thread group per tile
#define SCAN_BLOCKS (ROWS * SBPR)   // 1568
#define TG 3.0f                // speculative threshold; E[cand/tile] ~= 22
#define BCAP 96                // per-tile candidate cap (huge margin)
#define CAP_ROW (SBPR * BCAP)  // 4704
#define SLOTS_PT 19            // ceil(4704/256)

// ws layout (bytes), ~709 KB total footprint (proven in v12):
//   bm    : u8[SCAN_BLOCKS][THREADS]  @ 0       (401408)  always rewritten
//   pos16 : u16[SCAN_BLOCKS][BCAP]    @ 401408  (301056)  slots
//   bcnt  : i32[SCAN_BLOCKS]          @ 702464  (6272)    always rewritten
//   thr   : f32[ROWS]                 @ 708736  (128)
#define OFF_POS  401408
#define OFF_BCNT 702464
#define OFF_THR  708736

// Monotone order-preserving f32 -> u32 key (larger float -> larger key).
__device__ __forceinline__ uint32_t fkey(float x) {
    uint32_t u = __float_as_uint(x);
    return (u & 0x80000000u) ? ~u : (u | 0x80000000u);
}
__device__ __forceinline__ float fkey_inv(uint32_t k) {
    uint32_t u = (k & 0x80000000u) ? (k & 0x7FFFFFFFu) : ~k;
    return __uint_as_float(u);
}

// Pass 1: wave-specialized stream over one tile per block.
//   waves 0-3 (t = tid&255): pure read; load f4, fmax, bit in register,
//                            one u8 bitmap store per thread at the end.
//   waves 4-7 (t = tid&255): pure write; store zero f4 over the same tile.
// Bit b of (tile,t) covers f4 indices {2b*256+t, (2b+1)*256+t}.
__global__ __launch_bounds__(SCAN_THREADS) void k_scan(const float* __restrict__ in,
                                                       float* __restrict__ out,
                                                       uint8_t* __restrict__ bm) {
    const int bid = blockIdx.x;
    const int t = threadIdx.x & 255;
    const size_t base = (size_t)bid * TILE_F4 + t;
    if (threadIdx.x < 256) {
        // READ stream: nothing in this wave's loop but loads and VALU.
        const float4* p = (const float4*)in + base;
        uint32_t cm = 0;
#pragma unroll
        for (int it = 0; it < F4_PT; ++it) {
            const float4 d = p[it * 256];
            const float mx = fmaxf(fmaxf(d.x, d.y), fmaxf(d.z, d.w));
            cm |= (mx > TG) ? (1u << (it >> 1)) : 0u;
        }
        bm[(size_t)bid * 256 + t] = (uint8_t)cm;
    } else {
        // WRITE stream: nothing but stores.
        float4* q = (float4*)out + base;
        const float4 z = make_float4(0.f, 0.f, 0.f, 0.f);
#pragma unroll
        for (int it = 0; it < F4_PT; ++it)
            q[it * 256] = z;
    }
}

// Pass 2: per tile, decode bitmap and append candidate positions to slots.
__global__ __launch_bounds__(THREADS) void k_gather(const float* __restrict__ in,
                                                    const uint8_t* __restrict__ bm,
                                                    uint16_t* __restrict__ pos16,
                                                    int* __restrict__ bcnt) {
    __shared__ uint32_t lp[BCAP];
    __shared__ int lcnt;
    const int bid = blockIdx.x;
    if (threadIdx.x == 0) lcnt = 0;
    __syncthreads();
    const float4* p = (const float4*)in + (size_t)bid * TILE_F4;
    uint32_t cm = bm[(size_t)bid * THREADS + threadIdx.x];
    while (cm) {
        const int b = __builtin_ctz(cm);
        cm &= cm - 1;
#pragma unroll
        for (int half = 0; half < 2; ++half) {
            const uint32_t fi = (uint32_t)(2 * b + half) * THREADS + threadIdx.x;
            const float4 d = p[fi];
            const uint32_t e = fi * 4u;
            if (d.x > TG) { int j = atomicAdd(&lcnt, 1); if (j < BCAP) lp[j] = e + 0u; }
            if (d.y > TG) { int j = atomicAdd(&lcnt, 1); if (j < BCAP) lp[j] = e + 1u; }
            if (d.z > TG) { int j = atomicAdd(&lcnt, 1); if (j < BCAP) lp[j] = e + 2u; }
            if (d.w > TG) { int j = atomicAdd(&lcnt, 1); if (j < BCAP) lp[j] = e + 3u; }
        }
    }
    __syncthreads();
    const int c = lcnt;
    if (threadIdx.x == 0) bcnt[bid] = c;   // raw; overflow detected in k_sel
    const int cc = c < BCAP ? c : BCAP;
    for (int i = threadIdx.x; i < cc; i += THREADS)
        pos16[(size_t)bid * BCAP + i] = (uint16_t)lp[i];
}

// Parallel digit pick: histogram h[256] -> inclusive suffix scan across the
// 256 threads (Hillis-Steele, 8 steps) -> digit d with S[d] >= r > S[d+1].
__device__ __forceinline__ void pick_digit(uint32_t* h, int t, int r,
                                           int* sh_sel, int* sh_rank) {
#pragma unroll
    for (int off = 1; off < 256; off <<= 1) {
        uint32_t v = h[t] + ((t + off < 256) ? h[t + off] : 0u);
        __syncthreads();
        h[t] = v;
        __syncthreads();
    }
    const uint32_t Sd = h[t];
    const uint32_t Sd1 = (t < 255) ? h[t + 1] : 0u;
    if ((int)Sd >= r && (int)Sd1 < r) { *sh_sel = t; *sh_rank = r - (int)Sd1; }
    __syncthreads();
}

// Pass 3: per row: gather candidate keys (cache-resident input), exact
// 4x8-bit radix select of the n-th largest, scatter survivors into the
// zeroed output. Fallback (!ok): full-row radix + full-row masked write.
__global__ __launch_bounds__(THREADS) void k_sel(const float* __restrict__ in,
                                                 const int* __restrict__ n_ptr,
                                                 const int* __restrict__ bcnt,
                                                 const uint16_t* __restrict__ pos16,
                                                 float* __restrict__ out,
                                                 float* __restrict__ thr) {
    __shared__ int lb[SBPR];
    __shared__ uint32_t h[256];
    __shared__ int sh_sel, sh_rank, sh_m, sh_bad;
    const int row = blockIdx.x;
    const int t = threadIdx.x;
    const int n = *n_ptr;
    const float* rin = in + (size_t)row * ROW_LEN;
    float* rout = out + (size_t)row * ROW_LEN;

    if (t == 0) { sh_m = 0; sh_bad = 0; }
    __syncthreads();
    {
        int lsum = 0, lbad = 0;
        for (int b = t; b < SBPR; b += THREADS) {
            const int c = bcnt[row * SBPR + b];
            lbad |= (c > BCAP);
            const int cc = c < BCAP ? c : BCAP;
            lb[b] = cc;
            lsum += cc;
        }
        if (lsum) atomicAdd(&sh_m, lsum);
        if (lbad) atomicOr(&sh_bad, 1);
    }
    __syncthreads();
    const int m = sh_m;
    const bool ok = (!sh_bad) && (m >= n) && (n >= 1);

    if (ok) {
        // Coalesced slot load + gathered key fetch (cache-resident input).
        uint32_t key[SLOTS_PT];
        uint32_t ps[SLOTS_PT];
        bool val[SLOTS_PT];
#pragma unroll
        for (int j = 0; j < SLOTS_PT; ++j) {
            const int slot = j * THREADS + t;
            uint32_t k = 0, pp = 0; bool v = false;
            if (slot < CAP_ROW) {
                const int b = slot / BCAP;
                v = (slot - b * BCAP) < lb[b];
                if (v) {
                    pp = (uint32_t)b * TILE_EL + pos16[(size_t)(row * SBPR) * BCAP + slot];
                    k = fkey(rin[pp]);
                }
            }
            key[j] = k; ps[j] = pp; val[j] = v;
        }
        uint32_t prefix = 0, msk = 0;
        int r = n;
        for (int rd = 0; rd < 4; ++rd) {
            const int shn = 24 - rd * 8;
            h[t] = 0;
            __syncthreads();
#pragma unroll
            for (int j = 0; j < SLOTS_PT; ++j)
                if (val[j] && (key[j] & msk) == prefix)
                    atomicAdd(&h[(key[j] >> shn) & 255u], 1u);
            __syncthreads();
            pick_digit(h, t, r, &sh_sel, &sh_rank);
            prefix |= ((uint32_t)sh_sel) << shn;
            msk |= 255u << shn;
            r = sh_rank;
            __syncthreads();
        }
        // Scatter survivors (key >= prefix <=> value >= threshold).
#pragma unroll
        for (int j = 0; j < SLOTS_PT; ++j)
            if (val[j] && key[j] >= prefix)
                rout[ps[j]] = fkey_inv(key[j]);
        if (t == 0) thr[row] = fkey_inv(prefix);
    } else {
        // Exact fallback: full-row radix select + full-row masked write.
        uint32_t prefix = 0, msk = 0;
        int r = (n < 1) ? 1 : n;
        const float4* p = (const float4*)rin;
        for (int rd = 0; rd < 4; ++rd) {
            const int shn = 24 - rd * 8;
            h[t] = 0;
            __syncthreads();
            for (int i = t; i < ROW_LEN4; i += THREADS) {
                const float4 d = p[i];
                uint32_t k;
                k = fkey(d.x); if ((k & msk) == prefix) atomicAdd(&h[(k >> shn) & 255u], 1u);
                k = fkey(d.y); if ((k & msk) == prefix) atomicAdd(&h[(k >> shn) & 255u], 1u);
                k = fkey(d.z); if ((k & msk) == prefix) atomicAdd(&h[(k >> shn) & 255u], 1u);
                k = fkey(d.w); if ((k & msk) == prefix) atomicAdd(&h[(k >> shn) & 255u], 1u);
            }
            __syncthreads();
            pick_digit(h, t, r, &sh_sel, &sh_rank);
            prefix |= ((uint32_t)sh_sel) << shn;
            msk |= 255u << shn;
            r = sh_rank;
            __syncthreads();
        }
        const float tf = fkey_inv(prefix);
        float4* q = (float4*)rout;
        for (int i = t; i < ROW_LEN4; i += THREADS) {
            float4 d = p[i];
            d.x = (d.x >= tf) ? d.x : 0.0f;
            d.y = (d.y >= tf) ? d.y : 0.0f;
            d.z = (d.z >= tf) ? d.z : 0.0f;
            d.w = (d.w >= tf) ? d.w : 0.0f;
            q[i] = d;
        }
        if (t == 0) thr[row] = tf;
    }
}

extern "C" void kernel_launch(void* const* d_in, const int* in_sizes, int n_in,
                              void* d_out, int out_size, void* d_ws, size_t ws_size,
                              hipStream_t stream) {
    const float* in = (const float*)d_in[0];
    const int* n_ptr = (const int*)d_in[1];
    float* out = (float*)d_out;
    char* ws = (char*)d_ws;

    uint8_t* bm = (uint8_t*)ws;
    uint16_t* pos16 = (uint16_t*)(ws + OFF_POS);
    int* bcnt = (int*)(ws + OFF_BCNT);
    float* thr = (float*)(ws + OFF_THR);

    k_scan<<<SCAN_BLOCKS, SCAN_THREADS, 0, stream>>>(in, out, bm);
    k_gather<<<SCAN_BLOCKS, THREADS, 0, stream>>>(in, bm, pos16, bcnt);
    k_sel<<<ROWS, THREADS, 0, stream>>>(in, n_ptr, bcnt, pos16, out, thr);
}